// Round 6
// baseline (366.407 us; speedup 1.0000x reference)
//
#include <hip/hip_runtime.h>
#include <math.h>

#define OBSD 3584
#define NEGC -9e15f

typedef short short8 __attribute__((ext_vector_type(8)));
typedef float float4v __attribute__((ext_vector_type(4)));

// ---- ws element offsets (shorts unless _F) ----
#define WS_MT_S   0        // short: Mt bf16 [128][128]  (Mt[i][r] = M[r][i])
#define WS_U_F    8192     // float: u[128]
#define WS_W_F    8320     // float: w[128]
#define WS_C0_F   8448     // float: c0
#define WS_AW_F   8452     // float: aw_dr[64], aw_dk[64]
#define WS_WDMT_S 17160    // short: wdmT bf16 [128][16]
#define WS_WFT_S  19208    // short: WflatT bf16 [128][64]
#define WS_WC1H_S 32768    // short: Wc1T hi bf16 [64][4096]
#define WS_WC1L_S 294912   // short: Wc1T lo bf16 [64][4096]
#define WS_HD_S   557056   // short: HD bf16 [4096][4096] (fused path only)
#define WS_NEED_BYTES  1114112ull
#define WS_NEED2_BYTES 34668544ull

__device__ __forceinline__ float elu_f(float x) {
    return x > 0.f ? x : (__expf(x) - 1.f);
}
__device__ __forceinline__ short f2bf(float f) {
    union { float f; unsigned u; } v; v.f = f;
    unsigned u = v.u;
    unsigned r = (u + 0x7fffu + ((u >> 16) & 1u)) >> 16;
    return (short)r;
}
__device__ __forceinline__ float b2f(short s) {
    union { unsigned u; float f; } v; v.u = ((unsigned)(unsigned short)s) << 16;
    return v.f;
}
__device__ __forceinline__ unsigned pk2(float a, float b) {
    return (unsigned)(unsigned short)f2bf(a) | ((unsigned)(unsigned short)f2bf(b) << 16);
}

// =============== K0: all weight folding in one dispatch (82 blocks) ==========
// bi 0..15: Mt tiles; bi 16: u/w/c0; bi 17: aw + wdmT + WflatT;
// bi 18..81: Wc1 -> transposed bf16 hi/lo (gated by do_wc1)
__global__ __launch_bounds__(256) void setup_all(
    const float* __restrict__ W_drone, const float* __restrict__ W_dock,
    const float* __restrict__ a_src, const float* __restrict__ a_dst,
    const float* __restrict__ Wad, const float* __restrict__ Wak,
    const float* __restrict__ bad, const float* __restrict__ bak,
    const float* __restrict__ Wc1,
    float* __restrict__ wsf, short* __restrict__ wss, int do_wc1)
{
    __shared__ __align__(16) char smu[33792];
    const int t = threadIdx.x, bi = blockIdx.x;
    if (bi < 16) {
        float* sa = (float*)smu;              // [32][132]
        float* sb = (float*)(smu + 16896);    // [32][132]
        const int r0 = (bi >> 2) * 32, i0 = (bi & 3) * 32;
        #pragma unroll
        for (int qq = 0; qq < 4; ++qq) {
            int e = (t + 256 * qq) * 4;
            int r = e >> 7, cc = e & 127;
            *(float4*)&sa[r * 132 + cc] = *(const float4*)&Wad[(r0 + r) * 128 + cc];
            *(float4*)&sb[r * 132 + cc] = *(const float4*)&Wak[(i0 + r) * 128 + cc];
        }
        __syncthreads();
        int rr = (t >> 4) * 2, ii = (t & 15) * 2;
        float a00 = 0.f, a01 = 0.f, a10 = 0.f, a11 = 0.f;
        for (int c = 0; c < 128; ++c) {
            float x0 = sa[rr * 132 + c], x1 = sa[(rr + 1) * 132 + c];
            float y0 = sb[ii * 132 + c], y1 = sb[(ii + 1) * 132 + c];
            a00 += x0 * y0; a01 += x0 * y1; a10 += x1 * y0; a11 += x1 * y1;
        }
        wss[WS_MT_S + (i0 + ii) * 128 + (r0 + rr)]         = f2bf(a00);
        wss[WS_MT_S + (i0 + ii + 1) * 128 + (r0 + rr)]     = f2bf(a01);
        wss[WS_MT_S + (i0 + ii) * 128 + (r0 + rr + 1)]     = f2bf(a10);
        wss[WS_MT_S + (i0 + ii + 1) * 128 + (r0 + rr + 1)] = f2bf(a11);
    } else if (bi == 16) {
        if (t < 128) {
            float acc = 0.f;
            for (int c = 0; c < 128; ++c) acc += Wad[t * 128 + c] * bak[c];
            wsf[WS_U_F + t] = acc;
        } else {
            int j = t - 128;
            float acc = 0.f;
            for (int c = 0; c < 128; ++c) acc += Wak[j * 128 + c] * bad[c];
            wsf[WS_W_F + j] = acc;
        }
        if (t == 0) {
            float acc = 0.f;
            for (int c = 0; c < 128; ++c) acc += bad[c] * bak[c];
            wsf[WS_C0_F] = acc;
        }
    } else if (bi == 17) {
        if (t < 64) {
            int h = t >> 4, f = t & 15;
            const float* wrow = W_drone + h * 2048 + f * 128;
            const float* arow = a_src + h * 128;
            float acc = 0.f;
            for (int k = 0; k < 128; ++k) acc += wrow[k] * arow[k];
            wsf[WS_AW_F + t] = acc;
        } else if (t < 128) {
            int tt = t - 64;
            int h = tt >> 4, f = tt & 15;
            const float* wrow = W_dock + h * 2048 + f * 128;
            const float* arow = a_dst + h * 128;
            float acc = 0.f;
            for (int k = 0; k < 128; ++k) acc += wrow[k] * arow[k];
            wsf[WS_AW_F + 64 + tt] = acc;
        }
        for (int idx = t; idx < 2048; idx += 256) {
            int k2 = idx >> 4, f = idx & 15;
            float v = 0.25f * (W_dock[f * 128 + k2] + W_dock[2048 + f * 128 + k2]
                             + W_dock[4096 + f * 128 + k2] + W_dock[6144 + f * 128 + k2]);
            wss[WS_WDMT_S + k2 * 16 + f] = f2bf(v);
        }
        for (int idx = t; idx < 8192; idx += 256) {
            int k2 = idx >> 6, f64 = idx & 63;
            float v = W_dock[(f64 >> 4) * 2048 + (f64 & 15) * 128 + k2];
            wss[WS_WFT_S + k2 * 64 + f64] = f2bf(v);
        }
    } else {
        if (!do_wc1) return;
        float* tile = (float*)smu;            // [64][68]
        short* wc1h = wss + WS_WC1H_S;
        short* wc1l = wss + WS_WC1L_S;
        const int k0 = (bi - 18) * 64;
        {
            int r = t >> 2, c0 = (t & 3) * 16;
            const float4* src = (const float4*)&Wc1[(size_t)(k0 + r) * 64 + c0];
            #pragma unroll
            for (int u = 0; u < 4; ++u)
                *(float4*)&tile[r * 68 + c0 + 4 * u] = src[u];
        }
        __syncthreads();
        {
            int col = t >> 2, kk0 = (t & 3) * 16;
            short hi[16], lo[16];
            #pragma unroll
            for (int j = 0; j < 16; ++j) {
                float v = tile[(kk0 + j) * 68 + col];
                hi[j] = f2bf(v);
                lo[j] = f2bf(v - b2f(hi[j]));
            }
            uint4* dh = (uint4*)(wc1h + (size_t)col * 4096 + k0 + kk0);
            uint4* dl = (uint4*)(wc1l + (size_t)col * 4096 + k0 + kk0);
            dh[0] = *(uint4*)&hi[0]; dh[1] = *(uint4*)&hi[8];
            dl[0] = *(uint4*)&lo[0]; dl[1] = *(uint4*)&lo[8];
        }
    }
}

// =============== K13 fused: attention -> hd -> (HD to ws) -> logits ===========
__global__ __launch_bounds__(256, 2) void k13_fused(
    const float* __restrict__ obs,
    const float* __restrict__ wsf, const short* __restrict__ wss,
    short* __restrict__ hdg,            // HD in ws
    float* __restrict__ out_logits)
{
    __shared__ __align__(16) char sm[74240];
    short* sD     = (short*)(sm + 0);
    short* sK     = (short*)(sm + 1024);
    short* sAdj   = (short*)(sm + 3072);
    float* sAw    = (float*)(sm + 7680);
    float* sSrc   = (float*)(sm + 8192);
    float* sDst   = (float*)(sm + 8704);
    short* sAt    = (short*)(sm + 9728);
    short* sT     = (short*)(sm + 28160);
    short* sHd    = (short*)(sm + 32768);
    short* sWf    = (short*)(sm + 41472);
    // phase B aliases
    short* dockRm = (short*)(sm + 0);
    float* suL    = (float*)(sm + 8192);
    float* swL    = (float*)(sm + 8320);
    float* uL     = (float*)(sm + 8704);
    float* wL     = (float*)(sm + 9216);
    short* hkS    = (short*)(sm + 9728);
    short* wdmTS  = (short*)(sm + 28160);
    short* t2S    = (short*)(sm + 32768);
    short* MtS    = (short*)(sm + 41472);

    const int t = threadIdx.x;
    const int b = blockIdx.x;
    const float* obsrow = obs + (size_t)b * OBSD;
    const int L = t & 63, c = L & 15, q = L >> 4, w = t >> 6;

    #pragma unroll
    for (int i = 0; i < 4; ++i) {
        int q4 = t + 256 * i;
        if (q4 < 896) {
            float4 v = ((const float4*)obsrow)[q4];
            int e0 = q4 * 4;
            if (e0 < 512) {
                int n = e0 >> 4, f0 = e0 & 15;
                sD[(f0 + 0) * 32 + n] = f2bf(v.x);
                sD[(f0 + 1) * 32 + n] = f2bf(v.y);
                sD[(f0 + 2) * 32 + n] = f2bf(v.z);
                sD[(f0 + 3) * 32 + n] = f2bf(v.w);
            } else if (e0 < 1536) {
                int e = e0 - 512;
                int m = e >> 4, f0 = e & 15;
                sK[(f0 + 0) * 64 + m] = f2bf(v.x);
                sK[(f0 + 1) * 64 + m] = f2bf(v.y);
                sK[(f0 + 2) * 64 + m] = f2bf(v.z);
                sK[(f0 + 3) * 64 + m] = f2bf(v.w);
            } else {
                int e = e0 - 1536;
                int n = e >> 6, m0 = e & 63;
                uint2 pkd = { pk2(v.x, v.y), pk2(v.z, v.w) };
                *(uint2*)&sAdj[n * 72 + m0] = pkd;
            }
        }
    }
    #pragma unroll
    for (int i = 0; i < 4; ++i)
        ((uint4*)sWf)[t + 256 * i] = ((const uint4*)(wss + WS_WFT_S))[t + 256 * i];
    if (t < 128) sAw[t] = wsf[WS_AW_F + t];
    __syncthreads();

    if (t < 128) {
        int h = t >> 5, n = t & 31;
        float acc = 0.f;
        #pragma unroll
        for (int f = 0; f < 16; ++f) acc += b2f(sD[f * 32 + n]) * sAw[h * 16 + f];
        sSrc[h * 32 + n] = acc;
    }
    {
        int h = t >> 6, m = t & 63;
        float acc = 0.f;
        #pragma unroll
        for (int f = 0; f < 16; ++f) acc += b2f(sK[f * 64 + m]) * sAw[64 + h * 16 + f];
        sDst[h * 64 + m] = acc;
    }
    __syncthreads();

    {
        int row = t >> 1, j = t & 1;
        int h = row >> 5, n = row & 31, m0 = j * 32;
        float sv = sSrc[h * 32 + n];
        float e32[32];
        float pmax = -INFINITY;
        #pragma unroll
        for (int mm = 0; mm < 32; ++mm) {
            int m = m0 + mm;
            float e = sv + sDst[h * 64 + m];
            e = e > 0.f ? e : 0.2f * e;
            e = (b2f(sAdj[n * 72 + m]) > 0.f) ? e : NEGC;
            e32[mm] = e;
            pmax = fmaxf(pmax, e);
        }
        pmax = fmaxf(pmax, __shfl_xor(pmax, 1, 2));
        float psum = 0.f;
        #pragma unroll
        for (int mm = 0; mm < 32; ++mm) { e32[mm] = __expf(e32[mm] - pmax); psum += e32[mm]; }
        psum += __shfl_xor(psum, 1, 2);
        float rinv = 1.f / psum;
        unsigned* ab = (unsigned*)sAt;
        int ub = (h * 2304 + n * 72 + m0) >> 1;
        #pragma unroll
        for (int mm = 0; mm < 32; mm += 2)
            ab[ub + (mm >> 1)] = pk2(e32[mm] * rinv, e32[mm + 1] * rinv);
    }
    __syncthreads();

    {
        int h = w;
        float4v accT[2] = { {0,0,0,0}, {0,0,0,0} };
        #pragma unroll
        for (int mt = 0; mt < 2; ++mt)
            #pragma unroll
            for (int kq = 0; kq < 2; ++kq) {
                short8 a = *(const short8*)&sAt[h * 2304 + (mt * 16 + c) * 72 + kq * 32 + q * 8];
                short8 bb = *(const short8*)&sK[c * 64 + kq * 32 + q * 8];
                accT[mt] = __builtin_amdgcn_mfma_f32_16x16x32_bf16(a, bb, accT[mt], 0, 0, 0);
            }
        #pragma unroll
        for (int mt = 0; mt < 2; ++mt)
            #pragma unroll
            for (int i = 0; i < 4; ++i)
                sT[(mt * 16 + q * 4 + i) * 72 + h * 16 + c] = f2bf(accT[mt][i]);
    }
    __syncthreads();

    {
        int mt = w & 1, ntb = (w >> 1) * 4;
        float4v acc[4] = { {0,0,0,0}, {0,0,0,0}, {0,0,0,0}, {0,0,0,0} };
        #pragma unroll
        for (int kq = 0; kq < 2; ++kq) {
            short8 a = *(const short8*)&sT[(mt * 16 + c) * 72 + kq * 32 + q * 8];
            #pragma unroll
            for (int p = 0; p < 4; ++p) {
                short8 bb = *(const short8*)&sWf[((ntb + p) * 16 + c) * 64 + kq * 32 + q * 8];
                acc[p] = __builtin_amdgcn_mfma_f32_16x16x32_bf16(a, bb, acc[p], 0, 0, 0);
            }
        }
        #pragma unroll
        for (int p = 0; p < 4; ++p)
            #pragma unroll
            for (int i = 0; i < 4; ++i) {
                float v = elu_f(acc[p][i] * 0.25f);
                sHd[(mt * 16 + q * 4 + i) * 136 + (ntb + p) * 16 + c] = f2bf(v);
            }
    }
    __syncthreads();

    {
        int n = t >> 3, k2 = (t & 7) * 16;
        uint4 x0 = *(const uint4*)&sHd[n * 136 + k2];
        uint4 x1 = *(const uint4*)&sHd[n * 136 + k2 + 8];
        uint4* dst = (uint4*)(hdg + (size_t)b * 4096 + n * 128 + k2);
        dst[0] = x0; dst[1] = x1;
    }
    {
        float4 v = ((const float4*)obsrow)[128 + t];
        int m = t >> 2, f0 = (t & 3) * 4;
        uint2 pkd = { pk2(v.x, v.y), pk2(v.z, v.w) };
        *(uint2*)&dockRm[m * 16 + f0] = pkd;
    }
    ((uint4*)wdmTS)[t] = ((const uint4*)(wss + WS_WDMT_S))[t];
    #pragma unroll
    for (int i = 0; i < 8; ++i)
        ((uint4*)MtS)[t + 256 * i] = ((const uint4*)(wss + WS_MT_S))[t + 256 * i];
    if (t < 128) uL[t] = wsf[WS_U_F + t];
    else wL[t - 128] = wsf[WS_W_F + (t - 128)];
    __syncthreads();

    {
        int mt = w;
        short8 a;
        if (q < 2) a = *(const short8*)&dockRm[(mt * 16 + c) * 16 + q * 8];
        else a = short8{0, 0, 0, 0, 0, 0, 0, 0};
        float swp[4] = {0.f, 0.f, 0.f, 0.f};
        #pragma unroll
        for (int nt = 0; nt < 8; ++nt) {
            short8 bb;
            if (q < 2) bb = *(const short8*)&wdmTS[(nt * 16 + c) * 16 + q * 8];
            else bb = short8{0, 0, 0, 0, 0, 0, 0, 0};
            float4v acc = {0, 0, 0, 0};
            acc = __builtin_amdgcn_mfma_f32_16x16x32_bf16(a, bb, acc, 0, 0, 0);
            float wv = wL[nt * 16 + c];
            #pragma unroll
            for (int i = 0; i < 4; ++i) {
                float ev = elu_f(acc[i]);
                hkS[(mt * 16 + q * 4 + i) * 136 + nt * 16 + c] = f2bf(ev);
                swp[i] += ev * wv;
            }
        }
        #pragma unroll
        for (int i = 0; i < 4; ++i) {
            float sv = swp[i];
            sv += __shfl_xor(sv, 1, 16);
            sv += __shfl_xor(sv, 2, 16);
            sv += __shfl_xor(sv, 4, 16);
            sv += __shfl_xor(sv, 8, 16);
            if (c == 0) swL[mt * 16 + q * 4 + i] = sv;
        }
    }
    {
        int n = t >> 3, p = t & 7;
        float a = 0.f;
        #pragma unroll
        for (int kk = 0; kk < 16; kk += 2) {
            unsigned uu = *(const unsigned*)&sHd[n * 136 + p * 16 + kk];
            a += b2f((short)(uu & 0xffff)) * uL[p * 16 + kk]
               + b2f((short)(uu >> 16))   * uL[p * 16 + kk + 1];
        }
        a += __shfl_xor(a, 1, 8);
        a += __shfl_xor(a, 2, 8);
        a += __shfl_xor(a, 4, 8);
        if (p == 0) suL[n] = a;
    }
    __syncthreads();

    {
        int mt = w & 1, ntb = (w >> 1) * 4;
        float4v acc[4] = { {0,0,0,0}, {0,0,0,0}, {0,0,0,0}, {0,0,0,0} };
        #pragma unroll
        for (int kq = 0; kq < 4; ++kq) {
            short8 a = *(const short8*)&sHd[(mt * 16 + c) * 136 + kq * 32 + q * 8];
            #pragma unroll
            for (int p = 0; p < 4; ++p) {
                short8 bb = *(const short8*)&MtS[((ntb + p) * 16 + c) * 128 + kq * 32 + q * 8];
                acc[p] = __builtin_amdgcn_mfma_f32_16x16x32_bf16(a, bb, acc[p], 0, 0, 0);
            }
        }
        __syncthreads();
        #pragma unroll
        for (int p = 0; p < 4; ++p)
            #pragma unroll
            for (int i = 0; i < 4; ++i)
                t2S[(mt * 16 + q * 4 + i) * 136 + (ntb + p) * 16 + c] = f2bf(acc[p][i]);
    }
    __syncthreads();

    {
        const float c0v = wsf[WS_C0_F];
        int ntd = w;
        float* lg = out_logits + (size_t)b * 2048;
        #pragma unroll
        for (int mt = 0; mt < 2; ++mt) {
            float4v acc = {0, 0, 0, 0};
            #pragma unroll
            for (int kq = 0; kq < 4; ++kq) {
                short8 a  = *(const short8*)&t2S[(mt * 16 + c) * 136 + kq * 32 + q * 8];
                short8 bb = *(const short8*)&hkS[(ntd * 16 + c) * 136 + kq * 32 + q * 8];
                acc = __builtin_amdgcn_mfma_f32_16x16x32_bf16(a, bb, acc, 0, 0, 0);
            }
            int col = ntd * 16 + c;
            float swv = swL[col];
            #pragma unroll
            for (int i = 0; i < 4; ++i) {
                int row = mt * 16 + q * 4 + i;
                float val = acc[i] + suL[row] + swv + c0v;
                bool keep = b2f(sAdj[row * 72 + col]) > 0.f;
                lg[row * 64 + col] = keep ? val : NEGC;
            }
        }
    }
}

// =============== K2 (fast, R6): 512 blocks x 8 rows, register prefetch =======
// LDS: As[16][136] @0 (4352; rows 8-15 zeroed), Bh[64][136] @4352 (17408),
//      Bl @21760 (17408), bc1L @39168, wc2L @39424, red[32] @39680
__global__ __launch_bounds__(256) void k2_critic3(
    const short* __restrict__ hdg,
    const short* __restrict__ wc1h, const short* __restrict__ wc1l,
    const float* __restrict__ bc1,
    const float* __restrict__ Wc2, const float* __restrict__ bc2,
    float* __restrict__ out_values)
{
    __shared__ __align__(16) char sm[39936];
    short* As   = (short*)(sm + 0);
    short* Bh   = (short*)(sm + 4352);
    short* Bl   = (short*)(sm + 21760);
    float* bc1L = (float*)(sm + 39168);
    float* wc2L = (float*)(sm + 39424);
    float* red  = (float*)(sm + 39680);

    const int t = threadIdx.x;
    const int r0 = blockIdx.x * 8;
    const int L = t & 63, c = L & 15, q = L >> 4, w = t >> 6;

    if (t < 64) { bc1L[t] = bc1[t]; wc2L[t] = Wc2[t]; }
    // zero A rows 8..15 once (they feed unused acc rows)
    for (int idx = t; idx < 544; idx += 256)
        ((unsigned*)(As + 8 * 136))[idx] = 0u;

    const int rA  = t >> 4,  kkA = (t & 15) * 8;    // A: 8 rows x 128 k (t<128)
    const int colB = t >> 2, kbB = (t & 3) * 32;    // B: 64 cols x 128 k, 4 uint4 each

    uint4 pa;
    uint4 pbh[4], pbl[4];
    {   // prefetch it=0
        if (t < 128) pa = *(const uint4*)(hdg + (size_t)(r0 + rA) * 4096 + kkA);
        const uint4* srcH = (const uint4*)(wc1h + (size_t)colB * 4096 + kbB);
        const uint4* srcL = (const uint4*)(wc1l + (size_t)colB * 4096 + kbB);
        #pragma unroll
        for (int u = 0; u < 4; ++u) { pbh[u] = srcH[u]; pbl[u] = srcL[u]; }
    }

    float4v acc = {0, 0, 0, 0};

    for (int it = 0; it < 32; ++it) {
        __syncthreads();    // prior MFMA reads done before overwrite
        if (t < 128) *(uint4*)&As[rA * 136 + kkA] = pa;
        #pragma unroll
        for (int u = 0; u < 4; ++u) {
            *(uint4*)&Bh[colB * 136 + kbB + 8 * u] = pbh[u];
            *(uint4*)&Bl[colB * 136 + kbB + 8 * u] = pbl[u];
        }
        __syncthreads();
        if (it + 1 < 32) {   // prefetch next chunk; overlaps MFMA below
            const int kc = (it + 1) * 128;
            if (t < 128) pa = *(const uint4*)(hdg + (size_t)(r0 + rA) * 4096 + kc + kkA);
            const uint4* srcH = (const uint4*)(wc1h + (size_t)colB * 4096 + kc + kbB);
            const uint4* srcL = (const uint4*)(wc1l + (size_t)colB * 4096 + kc + kbB);
            #pragma unroll
            for (int u = 0; u < 4; ++u) { pbh[u] = srcH[u]; pbl[u] = srcL[u]; }
        }
        #pragma unroll
        for (int kq = 0; kq < 4; ++kq) {
            short8 a  = *(const short8*)&As[c * 136 + kq * 32 + q * 8];
            short8 bh = *(const short8*)&Bh[(w * 16 + c) * 136 + kq * 32 + q * 8];
            short8 bl = *(const short8*)&Bl[(w * 16 + c) * 136 + kq * 32 + q * 8];
            acc = __builtin_amdgcn_mfma_f32_16x16x32_bf16(a, bh, acc, 0, 0, 0);
            acc = __builtin_amdgcn_mfma_f32_16x16x32_bf16(a, bl, acc, 0, 0, 0);
        }
    }
    // epilogue: valid rows m = q*4+i < 8 (q<2); cols = w*16+c
    #pragma unroll
    for (int i = 0; i < 4; ++i) {
        float pre = acc[i] + bc1L[w * 16 + c];
        pre = fmaxf(pre, 0.f);
        float sv = pre * wc2L[w * 16 + c];
        sv += __shfl_xor(sv, 1, 16);
        sv += __shfl_xor(sv, 2, 16);
        sv += __shfl_xor(sv, 4, 16);
        sv += __shfl_xor(sv, 8, 16);
        if (c == 0 && q < 2) red[w * 8 + q * 4 + i] = sv;
    }
    __syncthreads();
    if (t < 8) {
        float v = red[t] + red[8 + t] + red[16 + t] + red[24 + t] + bc2[0];
        out_values[r0 + t] = v;
    }
}

// =============== Legacy small-ws path (unused when ws is large) ==============
__global__ __launch_bounds__(256, 2) void k1_attn_hd(
    const float* __restrict__ obs,
    const float* __restrict__ wsf, const short* __restrict__ wss,
    short* __restrict__ hdg)
{
    __shared__ __align__(16) char sm[57856];
    short* sD   = (short*)(sm + 0);
    short* sK   = (short*)(sm + 1024);
    short* sAdj = (short*)(sm + 3072);
    float* sAw  = (float*)(sm + 7680);
    float* sSrc = (float*)(sm + 8192);
    float* sDst = (float*)(sm + 8704);
    short* sAt  = (short*)(sm + 9728);
    short* sT   = (short*)(sm + 28160);
    short* sHd  = (short*)(sm + 32768);
    short* sWf  = (short*)(sm + 41472);

    const int t = threadIdx.x;
    const int b = blockIdx.x;
    const float* obsrow = obs + (size_t)b * OBSD;
    const int L = t & 63, c = L & 15, q = L >> 4, w = t >> 6;

    #pragma unroll
    for (int i = 0; i < 4; ++i) {
        int q4 = t + 256 * i;
        if (q4 < 896) {
            float4 v = ((const float4*)obsrow)[q4];
            int e0 = q4 * 4;
            if (e0 < 512) {
                int n = e0 >> 4, f0 = e0 & 15;
                sD[(f0 + 0) * 32 + n] = f2bf(v.x);
                sD[(f0 + 1) * 32 + n] = f2bf(v.y);
                sD[(f0 + 2) * 32 + n] = f2bf(v.z);
                sD[(f0 + 3) * 32 + n] = f2bf(v.w);
            } else if (e0 < 1536) {
                int e = e0 - 512;
                int m = e >> 4, f0 = e & 15;
                sK[(f0 + 0) * 64 + m] = f2bf(v.x);
                sK[(f0 + 1) * 64 + m] = f2bf(v.y);
                sK[(f0 + 2) * 64 + m] = f2bf(v.z);
                sK[(f0 + 3) * 64 + m] = f2bf(v.w);
            } else {
                int e = e0 - 1536;
                int n = e >> 6, m0 = e & 63;
                uint2 pkd = { pk2(v.x, v.y), pk2(v.z, v.w) };
                *(uint2*)&sAdj[n * 72 + m0] = pkd;
            }
        }
    }
    #pragma unroll
    for (int i = 0; i < 4; ++i)
        ((uint4*)sWf)[t + 256 * i] = ((const uint4*)(wss + WS_WFT_S))[t + 256 * i];
    if (t < 128) sAw[t] = wsf[WS_AW_F + t];
    __syncthreads();

    if (t < 128) {
        int h = t >> 5, n = t & 31;
        float acc = 0.f;
        #pragma unroll
        for (int f = 0; f < 16; ++f) acc += b2f(sD[f * 32 + n]) * sAw[h * 16 + f];
        sSrc[h * 32 + n] = acc;
    }
    {
        int h = t >> 6, m = t & 63;
        float acc = 0.f;
        #pragma unroll
        for (int f = 0; f < 16; ++f) acc += b2f(sK[f * 64 + m]) * sAw[64 + h * 16 + f];
        sDst[h * 64 + m] = acc;
    }
    __syncthreads();

    {
        int row = t >> 1, j = t & 1;
        int h = row >> 5, n = row & 31, m0 = j * 32;
        float sv = sSrc[h * 32 + n];
        float e32[32];
        float pmax = -INFINITY;
        #pragma unroll
        for (int mm = 0; mm < 32; ++mm) {
            int m = m0 + mm;
            float e = sv + sDst[h * 64 + m];
            e = e > 0.f ? e : 0.2f * e;
            e = (b2f(sAdj[n * 72 + m]) > 0.f) ? e : NEGC;
            e32[mm] = e;
            pmax = fmaxf(pmax, e);
        }
        pmax = fmaxf(pmax, __shfl_xor(pmax, 1, 2));
        float psum = 0.f;
        #pragma unroll
        for (int mm = 0; mm < 32; ++mm) { e32[mm] = __expf(e32[mm] - pmax); psum += e32[mm]; }
        psum += __shfl_xor(psum, 1, 2);
        float rinv = 1.f / psum;
        unsigned* ab = (unsigned*)sAt;
        int ub = (h * 2304 + n * 72 + m0) >> 1;
        #pragma unroll
        for (int mm = 0; mm < 32; mm += 2)
            ab[ub + (mm >> 1)] = pk2(e32[mm] * rinv, e32[mm + 1] * rinv);
    }
    __syncthreads();

    {
        int h = w;
        float4v accT[2] = { {0,0,0,0}, {0,0,0,0} };
        #pragma unroll
        for (int mt = 0; mt < 2; ++mt)
            #pragma unroll
            for (int kq = 0; kq < 2; ++kq) {
                short8 a = *(const short8*)&sAt[h * 2304 + (mt * 16 + c) * 72 + kq * 32 + q * 8];
                short8 bb = *(const short8*)&sK[c * 64 + kq * 32 + q * 8];
                accT[mt] = __builtin_amdgcn_mfma_f32_16x16x32_bf16(a, bb, accT[mt], 0, 0, 0);
            }
        #pragma unroll
        for (int mt = 0; mt < 2; ++mt)
            #pragma unroll
            for (int i = 0; i < 4; ++i)
                sT[(mt * 16 + q * 4 + i) * 72 + h * 16 + c] = f2bf(accT[mt][i]);
    }
    __syncthreads();

    {
        int mt = w & 1, ntb = (w >> 1) * 4;
        float4v acc[4] = { {0,0,0,0}, {0,0,0,0}, {0,0,0,0}, {0,0,0,0} };
        #pragma unroll
        for (int kq = 0; kq < 2; ++kq) {
            short8 a = *(const short8*)&sT[(mt * 16 + c) * 72 + kq * 32 + q * 8];
            #pragma unroll
            for (int p = 0; p < 4; ++p) {
                short8 bb = *(const short8*)&sWf[((ntb + p) * 16 + c) * 64 + kq * 32 + q * 8];
                acc[p] = __builtin_amdgcn_mfma_f32_16x16x32_bf16(a, bb, acc[p], 0, 0, 0);
            }
        }
        #pragma unroll
        for (int p = 0; p < 4; ++p)
            #pragma unroll
            for (int i = 0; i < 4; ++i) {
                float v = elu_f(acc[p][i] * 0.25f);
                sHd[(mt * 16 + q * 4 + i) * 136 + (ntb + p) * 16 + c] = f2bf(v);
            }
    }
    __syncthreads();

    {
        int n = t >> 3, k2 = (t & 7) * 16;
        uint4 x0 = *(const uint4*)&sHd[n * 136 + k2];
        uint4 x1 = *(const uint4*)&sHd[n * 136 + k2 + 8];
        uint4* dst = (uint4*)(hdg + (size_t)b * 4096 + n * 128 + k2);
        dst[0] = x0; dst[1] = x1;
    }
}

__global__ __launch_bounds__(256) void k2_critic(
    const short* __restrict__ hdg,
    const float* __restrict__ Wc1, const float* __restrict__ bc1,
    const float* __restrict__ Wc2, const float* __restrict__ bc2,
    float* __restrict__ out_values)
{
    __shared__ __align__(16) char sm[46592];
    short* As   = (short*)(sm + 0);
    float* Wst  = (float*)(sm + 9216);
    short* Bh   = (short*)(sm + 27648);
    short* Blo  = (short*)(sm + 36864);
    float* bc1L = (float*)(sm + 46080);
    float* wc2L = (float*)(sm + 46336);

    const int t = threadIdx.x;
    const int r0 = blockIdx.x * 64;
    const int L = t & 63, c = L & 15, q = L >> 4, w = t >> 6;

    if (t < 64) { bc1L[t] = bc1[t]; wc2L[t] = Wc2[t]; }

    float4v acc[4] = { {0,0,0,0}, {0,0,0,0}, {0,0,0,0}, {0,0,0,0} };

    for (int kc = 0; kc < 64; ++kc) {
        __syncthreads();
        {
            int r = t >> 2, kk0 = (t & 3) * 16;
            const uint4* src = (const uint4*)(hdg + (size_t)(r0 + r) * 4096 + kc * 64 + kk0);
            *(uint4*)&As[r * 72 + kk0]     = src[0];
            *(uint4*)&As[r * 72 + kk0 + 8] = src[1];
        }
        {
            int el = t >> 2, j0 = (t & 3) * 16;
            const float4* src = (const float4*)&Wc1[(size_t)(kc * 64 + el) * 64 + j0];
            #pragma unroll
            for (int u = 0; u < 4; ++u)
                *(float4*)&Wst[el * 72 + j0 + 4 * u] = src[u];
        }
        __syncthreads();
        {
            int j = t & 63, elb = (t >> 6) * 16;
            #pragma unroll
            for (int e = 0; e < 16; e += 2) {
                float v0 = Wst[(elb + e) * 72 + j];
                float v1 = Wst[(elb + e + 1) * 72 + j];
                short h0 = f2bf(v0), h1 = f2bf(v1);
                float l0 = v0 - b2f(h0), l1 = v1 - b2f(h1);
                *(unsigned*)&Bh[j * 72 + elb + e]  = (unsigned)(unsigned short)h0 | ((unsigned)(unsigned short)h1 << 16);
                *(unsigned*)&Blo[j * 72 + elb + e] = (unsigned)(unsigned short)f2bf(l0) | ((unsigned)(unsigned short)f2bf(l1) << 16);
            }
        }
        __syncthreads();
        #pragma unroll
        for (int kq = 0; kq < 2; ++kq) {
            short8 a = *(const short8*)&As[(w * 16 + c) * 72 + kq * 32 + q * 8];
            #pragma unroll
            for (int ct = 0; ct < 4; ++ct) {
                short8 bh = *(const short8*)&Bh[(ct * 16 + c) * 72 + kq * 32 + q * 8];
                short8 bl = *(const short8*)&Blo[(ct * 16 + c) * 72 + kq * 32 + q * 8];
                acc[ct] = __builtin_amdgcn_mfma_f32_16x16x32_bf16(a, bh, acc[ct], 0, 0, 0);
                acc[ct] = __builtin_amdgcn_mfma_f32_16x16x32_bf16(a, bl, acc[ct], 0, 0, 0);
            }
        }
    }
    float bc2v = bc2[0];
    #pragma unroll
    for (int i = 0; i < 4; ++i) {
        float sv = 0.f;
        #pragma unroll
        for (int ct = 0; ct < 4; ++ct) {
            float pre = acc[ct][i] + bc1L[ct * 16 + c];
            pre = fmaxf(pre, 0.f);
            sv += pre * wc2L[ct * 16 + c];
        }
        sv += __shfl_xor(sv, 1, 16);
        sv += __shfl_xor(sv, 2, 16);
        sv += __shfl_xor(sv, 4, 16);
        sv += __shfl_xor(sv, 8, 16);
        if (c == 0) out_values[r0 + w * 16 + q * 4 + i] = sv + bc2v;
    }
}

__global__ __launch_bounds__(256, 2) void k3_logits(
    const float* __restrict__ obs,
    const float* __restrict__ wsf, const short* __restrict__ wss,
    float* __restrict__ out_logits)
{
    __shared__ __align__(16) char sm[75648];
    short* dockRm = (short*)(sm + 0);
    short* adjBf  = (short*)(sm + 2048);
    short* hdS    = (short*)(sm + 6656);
    short* hkS    = (short*)(sm + 15360);
    short* wdmTS  = (short*)(sm + 32768);
    short* t2S    = (short*)(sm + 32768);
    float* suL    = (float*)(sm + 41472);
    float* swL    = (float*)(sm + 41600);
    float* uL     = (float*)(sm + 41856);
    float* wL     = (float*)(sm + 42368);
    short* MtS    = (short*)(sm + 42880);

    const int t = threadIdx.x;
    const int b = blockIdx.x;
    const float* obsrow = obs + (size_t)b * OBSD;
    short* hdg = (short*)out_logits;
    const int L = t & 63, c = L & 15, q = L >> 4, w = t >> 6;

    {
        int n = t >> 3, k2 = (t & 7) * 16;
        const uint4* src = (const uint4*)(hdg + (size_t)b * 4096 + n * 128 + k2);
        uint4 x0 = src[0], x1 = src[1];
        *(uint4*)&hdS[n * 136 + k2]     = x0;
        *(uint4*)&hdS[n * 136 + k2 + 8] = x1;
    }
    {
        float4 v = ((const float4*)obsrow)[128 + t];
        int m = t >> 2, f0 = (t & 3) * 4;
        uint2 pkd = { pk2(v.x, v.y), pk2(v.z, v.w) };
        *(uint2*)&dockRm[m * 16 + f0] = pkd;
    }
    #pragma unroll
    for (int i = 0; i < 2; ++i) {
        int q4 = 384 + t + 256 * i;
        if (q4 < 896) {
            float4 v = ((const float4*)obsrow)[q4];
            int e = q4 * 4 - 1536;
            int n = e >> 6, m0 = e & 63;
            uint2 pkd = { pk2(v.x, v.y), pk2(v.z, v.w) };
            *(uint2*)&adjBf[n * 72 + m0] = pkd;
        }
    }
    ((uint4*)wdmTS)[t] = ((const uint4*)(wss + WS_WDMT_S))[t];
    #pragma unroll
    for (int i = 0; i < 8; ++i)
        ((uint4*)MtS)[t + 256 * i] = ((const uint4*)(wss + WS_MT_S))[t + 256 * i];
    if (t < 128) uL[t] = wsf[WS_U_F + t];
    else wL[t - 128] = wsf[WS_W_F + (t - 128)];
    __syncthreads();

    {
        int mt = w;
        short8 a;
        if (q < 2) a = *(const short8*)&dockRm[(mt * 16 + c) * 16 + q * 8];
        else a = short8{0, 0, 0, 0, 0, 0, 0, 0};
        float swp[4] = {0.f, 0.f, 0.f, 0.f};
        #pragma unroll
        for (int nt = 0; nt < 8; ++nt) {
            short8 bb;
            if (q < 2) bb = *(const short8*)&wdmTS[(nt * 16 + c) * 16 + q * 8];
            else bb = short8{0, 0, 0, 0, 0, 0, 0, 0};
            float4v acc = {0, 0, 0, 0};
            acc = __builtin_amdgcn_mfma_f32_16x16x32_bf16(a, bb, acc, 0, 0, 0);
            float wv = wL[nt * 16 + c];
            #pragma unroll
            for (int i = 0; i < 4; ++i) {
                float ev = elu_f(acc[i]);
                hkS[(mt * 16 + q * 4 + i) * 136 + nt * 16 + c] = f2bf(ev);
                swp[i] += ev * wv;
            }
        }
        #pragma unroll
        for (int i = 0; i < 4; ++i) {
            float sv = swp[i];
            sv += __shfl_xor(sv, 1, 16);
            sv += __shfl_xor(sv, 2, 16);
            sv += __shfl_xor(sv, 4, 16);
            sv += __shfl_xor(sv, 8, 16);
            if (c == 0) swL[mt * 16 + q * 4 + i] = sv;
        }
    }
    {
        int n = t >> 3, p = t & 7;
        float a = 0.f;
        #pragma unroll
        for (int kk = 0; kk < 16; kk += 2) {
            unsigned uu = *(const unsigned*)&hdS[n * 136 + p * 16 + kk];
            a += b2f((short)(uu & 0xffff)) * uL[p * 16 + kk]
               + b2f((short)(uu >> 16))   * uL[p * 16 + kk + 1];
        }
        a += __shfl_xor(a, 1, 8);
        a += __shfl_xor(a, 2, 8);
        a += __shfl_xor(a, 4, 8);
        if (p == 0) suL[n] = a;
    }
    __syncthreads();

    {
        int mt = w & 1, ntb = (w >> 1) * 4;
        float4v acc[4] = { {0,0,0,0}, {0,0,0,0}, {0,0,0,0}, {0,0,0,0} };
        #pragma unroll
        for (int kq = 0; kq < 4; ++kq) {
            short8 a = *(const short8*)&hdS[(mt * 16 + c) * 136 + kq * 32 + q * 8];
            #pragma unroll
            for (int p = 0; p < 4; ++p) {
                short8 bb = *(const short8*)&MtS[((ntb + p) * 16 + c) * 128 + kq * 32 + q * 8];
                acc[p] = __builtin_amdgcn_mfma_f32_16x16x32_bf16(a, bb, acc[p], 0, 0, 0);
            }
        }
        __syncthreads();
        #pragma unroll
        for (int p = 0; p < 4; ++p)
            #pragma unroll
            for (int i = 0; i < 4; ++i)
                t2S[(mt * 16 + q * 4 + i) * 136 + (ntb + p) * 16 + c] = f2bf(acc[p][i]);
    }
    __syncthreads();

    {
        const float c0v = wsf[WS_C0_F];
        int ntd = w;
        float* lg = out_logits + (size_t)b * 2048;
        #pragma unroll
        for (int mt = 0; mt < 2; ++mt) {
            float4v acc = {0, 0, 0, 0};
            #pragma unroll
            for (int kq = 0; kq < 4; ++kq) {
                short8 a  = *(const short8*)&t2S[(mt * 16 + c) * 136 + kq * 32 + q * 8];
                short8 bb = *(const short8*)&hkS[(ntd * 16 + c) * 136 + kq * 32 + q * 8];
                acc = __builtin_amdgcn_mfma_f32_16x16x32_bf16(a, bb, acc, 0, 0, 0);
            }
            int col = ntd * 16 + c;
            float swv = swL[col];
            #pragma unroll
            for (int i = 0; i < 4; ++i) {
                int row = mt * 16 + q * 4 + i;
                float val = acc[i] + suL[row] + swv + c0v;
                bool keep = b2f(adjBf[row * 72 + col]) > 0.f;
                lg[row * 64 + col] = keep ? val : NEGC;
            }
        }
    }
}

extern "C" void kernel_launch(void* const* d_in, const int* in_sizes, int n_in,
                              void* d_out, int out_size, void* d_ws, size_t ws_size,
                              hipStream_t stream) {
    (void)in_sizes; (void)n_in; (void)out_size;
    const float* obs     = (const float*)d_in[0];
    const float* W_drone = (const float*)d_in[1];
    const float* W_dock  = (const float*)d_in[2];
    const float* a_src   = (const float*)d_in[3];
    const float* a_dst   = (const float*)d_in[4];
    const float* Wc1     = (const float*)d_in[5];
    const float* bc1     = (const float*)d_in[6];
    const float* Wc2     = (const float*)d_in[7];
    const float* bc2     = (const float*)d_in[8];
    const float* Wad     = (const float*)d_in[9];
    const float* bad     = (const float*)d_in[10];
    const float* Wak     = (const float*)d_in[11];
    const float* bak     = (const float*)d_in[12];
    float* out = (float*)d_out;
    float* wsf = (float*)d_ws;
    short* wss = (short*)d_ws;

    const bool ws_wc1 = (ws_size >= WS_NEED_BYTES);
    const bool ws_hd  = (ws_size >= WS_NEED2_BYTES);

    setup_all<<<dim3(82), dim3(256), 0, stream>>>(
        W_drone, W_dock, a_src, a_dst, Wad, Wak, bad, bak, Wc1,
        wsf, wss, ws_wc1 ? 1 : 0);

    if (ws_hd) {
        short* hdw = wss + WS_HD_S;
        k13_fused<<<dim3(4096), dim3(256), 0, stream>>>(
            obs, wsf, wss, hdw, out + 4096);
        k2_critic3<<<dim3(512), dim3(256), 0, stream>>>(
            hdw, wss + WS_WC1H_S, wss + WS_WC1L_S, bc1, Wc2, bc2, out);
    } else {
        short* hdg = (short*)(out + 4096);   // HD stashed in logits region
        k1_attn_hd<<<dim3(4096), dim3(256), 0, stream>>>(obs, wsf, wss, hdg);
        if (ws_wc1)
            k2_critic3<<<dim3(512), dim3(256), 0, stream>>>(
                hdg, wss + WS_WC1H_S, wss + WS_WC1L_S, bc1, Wc2, bc2, out);
        else
            k2_critic<<<dim3(64), dim3(256), 0, stream>>>(hdg, Wc1, bc1, Wc2, bc2, out);
        k3_logits<<<dim3(4096), dim3(256), 0, stream>>>(obs, wsf, wss, out + 4096);
    }
}

// Round 7
// 278.096 us; speedup vs baseline: 1.3176x; 1.3176x over previous
//
#include <hip/hip_runtime.h>
#include <math.h>

#define OBSD 3584
#define NEGC -9e15f

typedef short short8 __attribute__((ext_vector_type(8)));
typedef float float4v __attribute__((ext_vector_type(4)));

// ---- ws element offsets (shorts unless _F) ----
#define WS_MT_S   0        // short: Mt bf16 [128][128]  (Mt[i][r] = M[r][i])
#define WS_U_F    8192     // float: u[128]
#define WS_W_F    8320     // float: w[128]
#define WS_C0_F   8448     // float: c0
#define WS_AW_F   8452     // float: aw_dr[64], aw_dk[64]
#define WS_WDMT_S 17160    // short: wdmT bf16 [128][16]
#define WS_WFT_S  19208    // short: WflatT bf16 [128][64]
#define WS_WC1H_S 32768    // short: Wc1 hi bf16 PACKED [128 kq][64 col][32 k]
#define WS_WC1L_S 294912   // short: Wc1 lo bf16 PACKED (same layout)
#define WS_HD_S   557056   // short: HD bf16 [4096][4096] (fused path only)
#define WS_NEED_BYTES  1114112ull
#define WS_NEED2_BYTES 34668544ull

__device__ __forceinline__ float elu_f(float x) {
    return x > 0.f ? x : (__expf(x) - 1.f);
}
__device__ __forceinline__ short f2bf(float f) {
    union { float f; unsigned u; } v; v.f = f;
    unsigned u = v.u;
    unsigned r = (u + 0x7fffu + ((u >> 16) & 1u)) >> 16;
    return (short)r;
}
__device__ __forceinline__ float b2f(short s) {
    union { unsigned u; float f; } v; v.u = ((unsigned)(unsigned short)s) << 16;
    return v.f;
}
__device__ __forceinline__ unsigned pk2(float a, float b) {
    return (unsigned)(unsigned short)f2bf(a) | ((unsigned)(unsigned short)f2bf(b) << 16);
}

// =============== K0: all weight folding in one dispatch (82 blocks) ==========
// bi 0..15: Mt tiles; bi 16: u/w/c0; bi 17: aw + wdmT + WflatT;
// bi 18..81: Wc1 -> PACKED bf16 hi/lo fragments (gated by do_wc1)
__global__ __launch_bounds__(256) void setup_all(
    const float* __restrict__ W_drone, const float* __restrict__ W_dock,
    const float* __restrict__ a_src, const float* __restrict__ a_dst,
    const float* __restrict__ Wad, const float* __restrict__ Wak,
    const float* __restrict__ bad, const float* __restrict__ bak,
    const float* __restrict__ Wc1,
    float* __restrict__ wsf, short* __restrict__ wss, int do_wc1)
{
    __shared__ __align__(16) char smu[33792];
    const int t = threadIdx.x, bi = blockIdx.x;
    if (bi < 16) {
        float* sa = (float*)smu;              // [32][132]
        float* sb = (float*)(smu + 16896);    // [32][132]
        const int r0 = (bi >> 2) * 32, i0 = (bi & 3) * 32;
        #pragma unroll
        for (int qq = 0; qq < 4; ++qq) {
            int e = (t + 256 * qq) * 4;
            int r = e >> 7, cc = e & 127;
            *(float4*)&sa[r * 132 + cc] = *(const float4*)&Wad[(r0 + r) * 128 + cc];
            *(float4*)&sb[r * 132 + cc] = *(const float4*)&Wak[(i0 + r) * 128 + cc];
        }
        __syncthreads();
        int rr = (t >> 4) * 2, ii = (t & 15) * 2;
        float a00 = 0.f, a01 = 0.f, a10 = 0.f, a11 = 0.f;
        for (int c = 0; c < 128; ++c) {
            float x0 = sa[rr * 132 + c], x1 = sa[(rr + 1) * 132 + c];
            float y0 = sb[ii * 132 + c], y1 = sb[(ii + 1) * 132 + c];
            a00 += x0 * y0; a01 += x0 * y1; a10 += x1 * y0; a11 += x1 * y1;
        }
        wss[WS_MT_S + (i0 + ii) * 128 + (r0 + rr)]         = f2bf(a00);
        wss[WS_MT_S + (i0 + ii + 1) * 128 + (r0 + rr)]     = f2bf(a01);
        wss[WS_MT_S + (i0 + ii) * 128 + (r0 + rr + 1)]     = f2bf(a10);
        wss[WS_MT_S + (i0 + ii + 1) * 128 + (r0 + rr + 1)] = f2bf(a11);
    } else if (bi == 16) {
        if (t < 128) {
            float acc = 0.f;
            for (int c = 0; c < 128; ++c) acc += Wad[t * 128 + c] * bak[c];
            wsf[WS_U_F + t] = acc;
        } else {
            int j = t - 128;
            float acc = 0.f;
            for (int c = 0; c < 128; ++c) acc += Wak[j * 128 + c] * bad[c];
            wsf[WS_W_F + j] = acc;
        }
        if (t == 0) {
            float acc = 0.f;
            for (int c = 0; c < 128; ++c) acc += bad[c] * bak[c];
            wsf[WS_C0_F] = acc;
        }
    } else if (bi == 17) {
        if (t < 64) {
            int h = t >> 4, f = t & 15;
            const float* wrow = W_drone + h * 2048 + f * 128;
            const float* arow = a_src + h * 128;
            float acc = 0.f;
            for (int k = 0; k < 128; ++k) acc += wrow[k] * arow[k];
            wsf[WS_AW_F + t] = acc;
        } else if (t < 128) {
            int tt = t - 64;
            int h = tt >> 4, f = tt & 15;
            const float* wrow = W_dock + h * 2048 + f * 128;
            const float* arow = a_dst + h * 128;
            float acc = 0.f;
            for (int k = 0; k < 128; ++k) acc += wrow[k] * arow[k];
            wsf[WS_AW_F + 64 + tt] = acc;
        }
        for (int idx = t; idx < 2048; idx += 256) {
            int k2 = idx >> 4, f = idx & 15;
            float v = 0.25f * (W_dock[f * 128 + k2] + W_dock[2048 + f * 128 + k2]
                             + W_dock[4096 + f * 128 + k2] + W_dock[6144 + f * 128 + k2]);
            wss[WS_WDMT_S + k2 * 16 + f] = f2bf(v);
        }
        for (int idx = t; idx < 8192; idx += 256) {
            int k2 = idx >> 6, f64 = idx & 63;
            float v = W_dock[(f64 >> 4) * 2048 + (f64 & 15) * 128 + k2];
            wss[WS_WFT_S + k2 * 64 + f64] = f2bf(v);
        }
    } else {
        if (!do_wc1) return;
        float* tile = (float*)smu;            // [64][68]
        short* wc1h = wss + WS_WC1H_S;
        short* wc1l = wss + WS_WC1L_S;
        const int k0 = (bi - 18) * 64;
        {
            int r = t >> 2, c0 = (t & 3) * 16;   // coalesced fp32 read
            const float4* src = (const float4*)&Wc1[(size_t)(k0 + r) * 64 + c0];
            #pragma unroll
            for (int u = 0; u < 4; ++u)
                *(float4*)&tile[r * 68 + c0 + 4 * u] = src[u];
        }
        __syncthreads();
        {
            // packed write: element (k0+kk0+j, col) -> [kq][col][k&31]
            int col = t >> 2, kk0 = (t & 3) * 16;
            short hi[16], lo[16];
            #pragma unroll
            for (int j = 0; j < 16; ++j) {
                float v = tile[(kk0 + j) * 68 + col];
                hi[j] = f2bf(v);
                lo[j] = f2bf(v - b2f(hi[j]));
            }
            size_t base = (size_t)((k0 >> 5) + (kk0 >> 5)) * 2048 + col * 32 + (kk0 & 31);
            uint4* dh = (uint4*)(wc1h + base);
            uint4* dl = (uint4*)(wc1l + base);
            dh[0] = *(uint4*)&hi[0]; dh[1] = *(uint4*)&hi[8];
            dl[0] = *(uint4*)&lo[0]; dl[1] = *(uint4*)&lo[8];
        }
    }
}

// =============== K13 fused: attention -> hd -> (HD to ws) -> logits ===========
__global__ __launch_bounds__(256, 2) void k13_fused(
    const float* __restrict__ obs,
    const float* __restrict__ wsf, const short* __restrict__ wss,
    short* __restrict__ hdg,            // HD in ws
    float* __restrict__ out_logits)
{
    __shared__ __align__(16) char sm[74240];
    short* sD     = (short*)(sm + 0);
    short* sK     = (short*)(sm + 1024);
    short* sAdj   = (short*)(sm + 3072);
    float* sAw    = (float*)(sm + 7680);
    float* sSrc   = (float*)(sm + 8192);
    float* sDst   = (float*)(sm + 8704);
    short* sAt    = (short*)(sm + 9728);
    short* sT     = (short*)(sm + 28160);
    short* sHd    = (short*)(sm + 32768);
    short* sWf    = (short*)(sm + 41472);
    // phase B aliases
    short* dockRm = (short*)(sm + 0);
    float* suL    = (float*)(sm + 8192);
    float* swL    = (float*)(sm + 8320);
    float* uL     = (float*)(sm + 8704);
    float* wL     = (float*)(sm + 9216);
    short* hkS    = (short*)(sm + 9728);
    short* wdmTS  = (short*)(sm + 28160);
    short* t2S    = (short*)(sm + 32768);
    short* MtS    = (short*)(sm + 41472);

    const int t = threadIdx.x;
    const int b = blockIdx.x;
    const float* obsrow = obs + (size_t)b * OBSD;
    const int L = t & 63, c = L & 15, q = L >> 4, w = t >> 6;

    #pragma unroll
    for (int i = 0; i < 4; ++i) {
        int q4 = t + 256 * i;
        if (q4 < 896) {
            float4 v = ((const float4*)obsrow)[q4];
            int e0 = q4 * 4;
            if (e0 < 512) {
                int n = e0 >> 4, f0 = e0 & 15;
                sD[(f0 + 0) * 32 + n] = f2bf(v.x);
                sD[(f0 + 1) * 32 + n] = f2bf(v.y);
                sD[(f0 + 2) * 32 + n] = f2bf(v.z);
                sD[(f0 + 3) * 32 + n] = f2bf(v.w);
            } else if (e0 < 1536) {
                int e = e0 - 512;
                int m = e >> 4, f0 = e & 15;
                sK[(f0 + 0) * 64 + m] = f2bf(v.x);
                sK[(f0 + 1) * 64 + m] = f2bf(v.y);
                sK[(f0 + 2) * 64 + m] = f2bf(v.z);
                sK[(f0 + 3) * 64 + m] = f2bf(v.w);
            } else {
                int e = e0 - 1536;
                int n = e >> 6, m0 = e & 63;
                uint2 pkd = { pk2(v.x, v.y), pk2(v.z, v.w) };
                *(uint2*)&sAdj[n * 72 + m0] = pkd;
            }
        }
    }
    #pragma unroll
    for (int i = 0; i < 4; ++i)
        ((uint4*)sWf)[t + 256 * i] = ((const uint4*)(wss + WS_WFT_S))[t + 256 * i];
    if (t < 128) sAw[t] = wsf[WS_AW_F + t];
    __syncthreads();

    if (t < 128) {
        int h = t >> 5, n = t & 31;
        float acc = 0.f;
        #pragma unroll
        for (int f = 0; f < 16; ++f) acc += b2f(sD[f * 32 + n]) * sAw[h * 16 + f];
        sSrc[h * 32 + n] = acc;
    }
    {
        int h = t >> 6, m = t & 63;
        float acc = 0.f;
        #pragma unroll
        for (int f = 0; f < 16; ++f) acc += b2f(sK[f * 64 + m]) * sAw[64 + h * 16 + f];
        sDst[h * 64 + m] = acc;
    }
    __syncthreads();

    {
        int row = t >> 1, j = t & 1;
        int h = row >> 5, n = row & 31, m0 = j * 32;
        float sv = sSrc[h * 32 + n];
        float e32[32];
        float pmax = -INFINITY;
        #pragma unroll
        for (int mm = 0; mm < 32; ++mm) {
            int m = m0 + mm;
            float e = sv + sDst[h * 64 + m];
            e = e > 0.f ? e : 0.2f * e;
            e = (b2f(sAdj[n * 72 + m]) > 0.f) ? e : NEGC;
            e32[mm] = e;
            pmax = fmaxf(pmax, e);
        }
        pmax = fmaxf(pmax, __shfl_xor(pmax, 1, 2));
        float psum = 0.f;
        #pragma unroll
        for (int mm = 0; mm < 32; ++mm) { e32[mm] = __expf(e32[mm] - pmax); psum += e32[mm]; }
        psum += __shfl_xor(psum, 1, 2);
        float rinv = 1.f / psum;
        unsigned* ab = (unsigned*)sAt;
        int ub = (h * 2304 + n * 72 + m0) >> 1;
        #pragma unroll
        for (int mm = 0; mm < 32; mm += 2)
            ab[ub + (mm >> 1)] = pk2(e32[mm] * rinv, e32[mm + 1] * rinv);
    }
    __syncthreads();

    {
        int h = w;
        float4v accT[2] = { {0,0,0,0}, {0,0,0,0} };
        #pragma unroll
        for (int mt = 0; mt < 2; ++mt)
            #pragma unroll
            for (int kq = 0; kq < 2; ++kq) {
                short8 a = *(const short8*)&sAt[h * 2304 + (mt * 16 + c) * 72 + kq * 32 + q * 8];
                short8 bb = *(const short8*)&sK[c * 64 + kq * 32 + q * 8];
                accT[mt] = __builtin_amdgcn_mfma_f32_16x16x32_bf16(a, bb, accT[mt], 0, 0, 0);
            }
        #pragma unroll
        for (int mt = 0; mt < 2; ++mt)
            #pragma unroll
            for (int i = 0; i < 4; ++i)
                sT[(mt * 16 + q * 4 + i) * 72 + h * 16 + c] = f2bf(accT[mt][i]);
    }
    __syncthreads();

    {
        int mt = w & 1, ntb = (w >> 1) * 4;
        float4v acc[4] = { {0,0,0,0}, {0,0,0,0}, {0,0,0,0}, {0,0,0,0} };
        #pragma unroll
        for (int kq = 0; kq < 2; ++kq) {
            short8 a = *(const short8*)&sT[(mt * 16 + c) * 72 + kq * 32 + q * 8];
            #pragma unroll
            for (int p = 0; p < 4; ++p) {
                short8 bb = *(const short8*)&sWf[((ntb + p) * 16 + c) * 64 + kq * 32 + q * 8];
                acc[p] = __builtin_amdgcn_mfma_f32_16x16x32_bf16(a, bb, acc[p], 0, 0, 0);
            }
        }
        #pragma unroll
        for (int p = 0; p < 4; ++p)
            #pragma unroll
            for (int i = 0; i < 4; ++i) {
                float v = elu_f(acc[p][i] * 0.25f);
                sHd[(mt * 16 + q * 4 + i) * 136 + (ntb + p) * 16 + c] = f2bf(v);
            }
    }
    __syncthreads();

    {
        int n = t >> 3, k2 = (t & 7) * 16;
        uint4 x0 = *(const uint4*)&sHd[n * 136 + k2];
        uint4 x1 = *(const uint4*)&sHd[n * 136 + k2 + 8];
        uint4* dst = (uint4*)(hdg + (size_t)b * 4096 + n * 128 + k2);
        dst[0] = x0; dst[1] = x1;
    }
    {
        float4 v = ((const float4*)obsrow)[128 + t];
        int m = t >> 2, f0 = (t & 3) * 4;
        uint2 pkd = { pk2(v.x, v.y), pk2(v.z, v.w) };
        *(uint2*)&dockRm[m * 16 + f0] = pkd;
    }
    ((uint4*)wdmTS)[t] = ((const uint4*)(wss + WS_WDMT_S))[t];
    #pragma unroll
    for (int i = 0; i < 8; ++i)
        ((uint4*)MtS)[t + 256 * i] = ((const uint4*)(wss + WS_MT_S))[t + 256 * i];
    if (t < 128) uL[t] = wsf[WS_U_F + t];
    else wL[t - 128] = wsf[WS_W_F + (t - 128)];
    __syncthreads();

    {
        int mt = w;
        short8 a;
        if (q < 2) a = *(const short8*)&dockRm[(mt * 16 + c) * 16 + q * 8];
        else a = short8{0, 0, 0, 0, 0, 0, 0, 0};
        float swp[4] = {0.f, 0.f, 0.f, 0.f};
        #pragma unroll
        for (int nt = 0; nt < 8; ++nt) {
            short8 bb;
            if (q < 2) bb = *(const short8*)&wdmTS[(nt * 16 + c) * 16 + q * 8];
            else bb = short8{0, 0, 0, 0, 0, 0, 0, 0};
            float4v acc = {0, 0, 0, 0};
            acc = __builtin_amdgcn_mfma_f32_16x16x32_bf16(a, bb, acc, 0, 0, 0);
            float wv = wL[nt * 16 + c];
            #pragma unroll
            for (int i = 0; i < 4; ++i) {
                float ev = elu_f(acc[i]);
                hkS[(mt * 16 + q * 4 + i) * 136 + nt * 16 + c] = f2bf(ev);
                swp[i] += ev * wv;
            }
        }
        #pragma unroll
        for (int i = 0; i < 4; ++i) {
            float sv = swp[i];
            sv += __shfl_xor(sv, 1, 16);
            sv += __shfl_xor(sv, 2, 16);
            sv += __shfl_xor(sv, 4, 16);
            sv += __shfl_xor(sv, 8, 16);
            if (c == 0) swL[mt * 16 + q * 4 + i] = sv;
        }
    }
    {
        int n = t >> 3, p = t & 7;
        float a = 0.f;
        #pragma unroll
        for (int kk = 0; kk < 16; kk += 2) {
            unsigned uu = *(const unsigned*)&sHd[n * 136 + p * 16 + kk];
            a += b2f((short)(uu & 0xffff)) * uL[p * 16 + kk]
               + b2f((short)(uu >> 16))   * uL[p * 16 + kk + 1];
        }
        a += __shfl_xor(a, 1, 8);
        a += __shfl_xor(a, 2, 8);
        a += __shfl_xor(a, 4, 8);
        if (p == 0) suL[n] = a;
    }
    __syncthreads();

    {
        int mt = w & 1, ntb = (w >> 1) * 4;
        float4v acc[4] = { {0,0,0,0}, {0,0,0,0}, {0,0,0,0}, {0,0,0,0} };
        #pragma unroll
        for (int kq = 0; kq < 4; ++kq) {
            short8 a = *(const short8*)&sHd[(mt * 16 + c) * 136 + kq * 32 + q * 8];
            #pragma unroll
            for (int p = 0; p < 4; ++p) {
                short8 bb = *(const short8*)&MtS[((ntb + p) * 16 + c) * 128 + kq * 32 + q * 8];
                acc[p] = __builtin_amdgcn_mfma_f32_16x16x32_bf16(a, bb, acc[p], 0, 0, 0);
            }
        }
        __syncthreads();
        #pragma unroll
        for (int p = 0; p < 4; ++p)
            #pragma unroll
            for (int i = 0; i < 4; ++i)
                t2S[(mt * 16 + q * 4 + i) * 136 + (ntb + p) * 16 + c] = f2bf(acc[p][i]);
    }
    __syncthreads();

    {
        const float c0v = wsf[WS_C0_F];
        int ntd = w;
        float* lg = out_logits + (size_t)b * 2048;
        #pragma unroll
        for (int mt = 0; mt < 2; ++mt) {
            float4v acc = {0, 0, 0, 0};
            #pragma unroll
            for (int kq = 0; kq < 4; ++kq) {
                short8 a  = *(const short8*)&t2S[(mt * 16 + c) * 136 + kq * 32 + q * 8];
                short8 bb = *(const short8*)&hkS[(ntd * 16 + c) * 136 + kq * 32 + q * 8];
                acc = __builtin_amdgcn_mfma_f32_16x16x32_bf16(a, bb, acc, 0, 0, 0);
            }
            int col = ntd * 16 + c;
            float swv = swL[col];
            #pragma unroll
            for (int i = 0; i < 4; ++i) {
                int row = mt * 16 + q * 4 + i;
                float val = acc[i] + suL[row] + swv + c0v;
                bool keep = b2f(sAdj[row * 72 + col]) > 0.f;
                lg[row * 64 + col] = keep ? val : NEGC;
            }
        }
    }
}

// =============== K2 (R7): barrier-free split-K critic ===============
// 256 blocks x 16 rows. Wave w owns K-range [w*1024, +1024), accumulates in
// registers with B read DIRECTLY from packed global fragments (no LDS, no
// barriers in the K-loop). One final LDS reduce across the 4 K-splits.
__global__ __launch_bounds__(256, 2) void k2_critic4(
    const short* __restrict__ hdg,
    const short* __restrict__ wc1h, const short* __restrict__ wc1l,
    const float* __restrict__ bc1,
    const float* __restrict__ Wc2, const float* __restrict__ bc2,
    float* __restrict__ out_values)
{
    __shared__ float part[4 * 16 * 64];   // 16 KB fp32 partials
    const int t = threadIdx.x;
    const int r0 = blockIdx.x * 16;
    const int L = t & 63, c = L & 15, q = L >> 4, w = t >> 6;

    float4v acc[4] = { {0,0,0,0}, {0,0,0,0}, {0,0,0,0}, {0,0,0,0} };

    // A: lane c supplies row r0+c; k = w*1024 + kq*32 + q*8
    const short* aptr = hdg + (size_t)(r0 + c) * 4096 + w * 1024 + q * 8;
    // B packed: [kq][col][32k]; col-tile ct -> +ct*512; this wave's kq base = w*32
    const size_t bbase = (size_t)(w * 32) * 2048 + c * 32 + q * 8;

    #pragma unroll 4
    for (int kq = 0; kq < 32; ++kq) {
        short8 a = *(const short8*)(aptr + kq * 32);
        const size_t bo = bbase + (size_t)kq * 2048;
        #pragma unroll
        for (int ct = 0; ct < 4; ++ct) {
            short8 bh = *(const short8*)(wc1h + bo + ct * 512);
            short8 bl = *(const short8*)(wc1l + bo + ct * 512);
            acc[ct] = __builtin_amdgcn_mfma_f32_16x16x32_bf16(a, bh, acc[ct], 0, 0, 0);
            acc[ct] = __builtin_amdgcn_mfma_f32_16x16x32_bf16(a, bl, acc[ct], 0, 0, 0);
        }
    }
    // partials: D cell (row=q*4+i, col=ct*16+c) for this wave's K-chunk
    #pragma unroll
    for (int ct = 0; ct < 4; ++ct)
        #pragma unroll
        for (int i = 0; i < 4; ++i)
            part[w * 1024 + (q * 4 + i) * 64 + ct * 16 + c] = acc[ct][i];
    __syncthreads();
    {
        int row = t >> 4, cg = t & 15;
        float v = 0.f;
        #pragma unroll
        for (int cc = 0; cc < 4; ++cc) {
            int col = cg * 4 + cc;
            float s = part[row * 64 + col] + part[1024 + row * 64 + col]
                    + part[2048 + row * 64 + col] + part[3072 + row * 64 + col];
            s += bc1[col];
            s = fmaxf(s, 0.f);
            v += s * Wc2[col];
        }
        v += __shfl_xor(v, 1, 16);
        v += __shfl_xor(v, 2, 16);
        v += __shfl_xor(v, 4, 16);
        v += __shfl_xor(v, 8, 16);
        if (cg == 0) out_values[r0 + row] = v + bc2[0];
    }
}

// =============== Legacy small-ws path (unused when ws is large) ==============
__global__ __launch_bounds__(256, 2) void k1_attn_hd(
    const float* __restrict__ obs,
    const float* __restrict__ wsf, const short* __restrict__ wss,
    short* __restrict__ hdg)
{
    __shared__ __align__(16) char sm[57856];
    short* sD   = (short*)(sm + 0);
    short* sK   = (short*)(sm + 1024);
    short* sAdj = (short*)(sm + 3072);
    float* sAw  = (float*)(sm + 7680);
    float* sSrc = (float*)(sm + 8192);
    float* sDst = (float*)(sm + 8704);
    short* sAt  = (short*)(sm + 9728);
    short* sT   = (short*)(sm + 28160);
    short* sHd  = (short*)(sm + 32768);
    short* sWf  = (short*)(sm + 41472);

    const int t = threadIdx.x;
    const int b = blockIdx.x;
    const float* obsrow = obs + (size_t)b * OBSD;
    const int L = t & 63, c = L & 15, q = L >> 4, w = t >> 6;

    #pragma unroll
    for (int i = 0; i < 4; ++i) {
        int q4 = t + 256 * i;
        if (q4 < 896) {
            float4 v = ((const float4*)obsrow)[q4];
            int e0 = q4 * 4;
            if (e0 < 512) {
                int n = e0 >> 4, f0 = e0 & 15;
                sD[(f0 + 0) * 32 + n] = f2bf(v.x);
                sD[(f0 + 1) * 32 + n] = f2bf(v.y);
                sD[(f0 + 2) * 32 + n] = f2bf(v.z);
                sD[(f0 + 3) * 32 + n] = f2bf(v.w);
            } else if (e0 < 1536) {
                int e = e0 - 512;
                int m = e >> 4, f0 = e & 15;
                sK[(f0 + 0) * 64 + m] = f2bf(v.x);
                sK[(f0 + 1) * 64 + m] = f2bf(v.y);
                sK[(f0 + 2) * 64 + m] = f2bf(v.z);
                sK[(f0 + 3) * 64 + m] = f2bf(v.w);
            } else {
                int e = e0 - 1536;
                int n = e >> 6, m0 = e & 63;
                uint2 pkd = { pk2(v.x, v.y), pk2(v.z, v.w) };
                *(uint2*)&sAdj[n * 72 + m0] = pkd;
            }
        }
    }
    #pragma unroll
    for (int i = 0; i < 4; ++i)
        ((uint4*)sWf)[t + 256 * i] = ((const uint4*)(wss + WS_WFT_S))[t + 256 * i];
    if (t < 128) sAw[t] = wsf[WS_AW_F + t];
    __syncthreads();

    if (t < 128) {
        int h = t >> 5, n = t & 31;
        float acc = 0.f;
        #pragma unroll
        for (int f = 0; f < 16; ++f) acc += b2f(sD[f * 32 + n]) * sAw[h * 16 + f];
        sSrc[h * 32 + n] = acc;
    }
    {
        int h = t >> 6, m = t & 63;
        float acc = 0.f;
        #pragma unroll
        for (int f = 0; f < 16; ++f) acc += b2f(sK[f * 64 + m]) * sAw[64 + h * 16 + f];
        sDst[h * 64 + m] = acc;
    }
    __syncthreads();

    {
        int row = t >> 1, j = t & 1;
        int h = row >> 5, n = row & 31, m0 = j * 32;
        float sv = sSrc[h * 32 + n];
        float e32[32];
        float pmax = -INFINITY;
        #pragma unroll
        for (int mm = 0; mm < 32; ++mm) {
            int m = m0 + mm;
            float e = sv + sDst[h * 64 + m];
            e = e > 0.f ? e : 0.2f * e;
            e = (b2f(sAdj[n * 72 + m]) > 0.f) ? e : NEGC;
            e32[mm] = e;
            pmax = fmaxf(pmax, e);
        }
        pmax = fmaxf(pmax, __shfl_xor(pmax, 1, 2));
        float psum = 0.f;
        #pragma unroll
        for (int mm = 0; mm < 32; ++mm) { e32[mm] = __expf(e32[mm] - pmax); psum += e32[mm]; }
        psum += __shfl_xor(psum, 1, 2);
        float rinv = 1.f / psum;
        unsigned* ab = (unsigned*)sAt;
        int ub = (h * 2304 + n * 72 + m0) >> 1;
        #pragma unroll
        for (int mm = 0; mm < 32; mm += 2)
            ab[ub + (mm >> 1)] = pk2(e32[mm] * rinv, e32[mm + 1] * rinv);
    }
    __syncthreads();

    {
        int h = w;
        float4v accT[2] = { {0,0,0,0}, {0,0,0,0} };
        #pragma unroll
        for (int mt = 0; mt < 2; ++mt)
            #pragma unroll
            for (int kq = 0; kq < 2; ++kq) {
                short8 a = *(const short8*)&sAt[h * 2304 + (mt * 16 + c) * 72 + kq * 32 + q * 8];
                short8 bb = *(const short8*)&sK[c * 64 + kq * 32 + q * 8];
                accT[mt] = __builtin_amdgcn_mfma_f32_16x16x32_bf16(a, bb, accT[mt], 0, 0, 0);
            }
        #pragma unroll
        for (int mt = 0; mt < 2; ++mt)
            #pragma unroll
            for (int i = 0; i < 4; ++i)
                sT[(mt * 16 + q * 4 + i) * 72 + h * 16 + c] = f2bf(accT[mt][i]);
    }
    __syncthreads();

    {
        int mt = w & 1, ntb = (w >> 1) * 4;
        float4v acc[4] = { {0,0,0,0}, {0,0,0,0}, {0,0,0,0}, {0,0,0,0} };
        #pragma unroll
        for (int kq = 0; kq < 2; ++kq) {
            short8 a = *(const short8*)&sT[(mt * 16 + c) * 72 + kq * 32 + q * 8];
            #pragma unroll
            for (int p = 0; p < 4; ++p) {
                short8 bb = *(const short8*)&sWf[((ntb + p) * 16 + c) * 64 + kq * 32 + q * 8];
                acc[p] = __builtin_amdgcn_mfma_f32_16x16x32_bf16(a, bb, acc[p], 0, 0, 0);
            }
        }
        #pragma unroll
        for (int p = 0; p < 4; ++p)
            #pragma unroll
            for (int i = 0; i < 4; ++i) {
                float v = elu_f(acc[p][i] * 0.25f);
                sHd[(mt * 16 + q * 4 + i) * 136 + (ntb + p) * 16 + c] = f2bf(v);
            }
    }
    __syncthreads();

    {
        int n = t >> 3, k2 = (t & 7) * 16;
        uint4 x0 = *(const uint4*)&sHd[n * 136 + k2];
        uint4 x1 = *(const uint4*)&sHd[n * 136 + k2 + 8];
        uint4* dst = (uint4*)(hdg + (size_t)b * 4096 + n * 128 + k2);
        dst[0] = x0; dst[1] = x1;
    }
}

__global__ __launch_bounds__(256) void k2_critic(
    const short* __restrict__ hdg,
    const float* __restrict__ Wc1, const float* __restrict__ bc1,
    const float* __restrict__ Wc2, const float* __restrict__ bc2,
    float* __restrict__ out_values)
{
    __shared__ __align__(16) char sm[46592];
    short* As   = (short*)(sm + 0);
    float* Wst  = (float*)(sm + 9216);
    short* Bh   = (short*)(sm + 27648);
    short* Blo  = (short*)(sm + 36864);
    float* bc1L = (float*)(sm + 46080);
    float* wc2L = (float*)(sm + 46336);

    const int t = threadIdx.x;
    const int r0 = blockIdx.x * 64;
    const int L = t & 63, c = L & 15, q = L >> 4, w = t >> 6;

    if (t < 64) { bc1L[t] = bc1[t]; wc2L[t] = Wc2[t]; }

    float4v acc[4] = { {0,0,0,0}, {0,0,0,0}, {0,0,0,0}, {0,0,0,0} };

    for (int kc = 0; kc < 64; ++kc) {
        __syncthreads();
        {
            int r = t >> 2, kk0 = (t & 3) * 16;
            const uint4* src = (const uint4*)(hdg + (size_t)(r0 + r) * 4096 + kc * 64 + kk0);
            *(uint4*)&As[r * 72 + kk0]     = src[0];
            *(uint4*)&As[r * 72 + kk0 + 8] = src[1];
        }
        {
            int el = t >> 2, j0 = (t & 3) * 16;
            const float4* src = (const float4*)&Wc1[(size_t)(kc * 64 + el) * 64 + j0];
            #pragma unroll
            for (int u = 0; u < 4; ++u)
                *(float4*)&Wst[el * 72 + j0 + 4 * u] = src[u];
        }
        __syncthreads();
        {
            int j = t & 63, elb = (t >> 6) * 16;
            #pragma unroll
            for (int e = 0; e < 16; e += 2) {
                float v0 = Wst[(elb + e) * 72 + j];
                float v1 = Wst[(elb + e + 1) * 72 + j];
                short h0 = f2bf(v0), h1 = f2bf(v1);
                float l0 = v0 - b2f(h0), l1 = v1 - b2f(h1);
                *(unsigned*)&Bh[j * 72 + elb + e]  = (unsigned)(unsigned short)h0 | ((unsigned)(unsigned short)h1 << 16);
                *(unsigned*)&Blo[j * 72 + elb + e] = (unsigned)(unsigned short)f2bf(l0) | ((unsigned)(unsigned short)f2bf(l1) << 16);
            }
        }
        __syncthreads();
        #pragma unroll
        for (int kq = 0; kq < 2; ++kq) {
            short8 a = *(const short8*)&As[(w * 16 + c) * 72 + kq * 32 + q * 8];
            #pragma unroll
            for (int ct = 0; ct < 4; ++ct) {
                short8 bh = *(const short8*)&Bh[(ct * 16 + c) * 72 + kq * 32 + q * 8];
                short8 bl = *(const short8*)&Blo[(ct * 16 + c) * 72 + kq * 32 + q * 8];
                acc[ct] = __builtin_amdgcn_mfma_f32_16x16x32_bf16(a, bh, acc[ct], 0, 0, 0);
                acc[ct] = __builtin_amdgcn_mfma_f32_16x16x32_bf16(a, bl, acc[ct], 0, 0, 0);
            }
        }
    }
    float bc2v = bc2[0];
    #pragma unroll
    for (int i = 0; i < 4; ++i) {
        float sv = 0.f;
        #pragma unroll
        for (int ct = 0; ct < 4; ++ct) {
            float pre = acc[ct][i] + bc1L[ct * 16 + c];
            pre = fmaxf(pre, 0.f);
            sv += pre * wc2L[ct * 16 + c];
        }
        sv += __shfl_xor(sv, 1, 16);
        sv += __shfl_xor(sv, 2, 16);
        sv += __shfl_xor(sv, 4, 16);
        sv += __shfl_xor(sv, 8, 16);
        if (c == 0) out_values[r0 + w * 16 + q * 4 + i] = sv + bc2v;
    }
}

__global__ __launch_bounds__(256, 2) void k3_logits(
    const float* __restrict__ obs,
    const float* __restrict__ wsf, const short* __restrict__ wss,
    float* __restrict__ out_logits)
{
    __shared__ __align__(16) char sm[75648];
    short* dockRm = (short*)(sm + 0);
    short* adjBf  = (short*)(sm + 2048);
    short* hdS    = (short*)(sm + 6656);
    short* hkS    = (short*)(sm + 15360);
    short* wdmTS  = (short*)(sm + 32768);
    short* t2S    = (short*)(sm + 32768);
    float* suL    = (float*)(sm + 41472);
    float* swL    = (float*)(sm + 41600);
    float* uL     = (float*)(sm + 41856);
    float* wL     = (float*)(sm + 42368);
    short* MtS    = (short*)(sm + 42880);

    const int t = threadIdx.x;
    const int b = blockIdx.x;
    const float* obsrow = obs + (size_t)b * OBSD;
    short* hdg = (short*)out_logits;
    const int L = t & 63, c = L & 15, q = L >> 4, w = t >> 6;

    {
        int n = t >> 3, k2 = (t & 7) * 16;
        const uint4* src = (const uint4*)(hdg + (size_t)b * 4096 + n * 128 + k2);
        uint4 x0 = src[0], x1 = src[1];
        *(uint4*)&hdS[n * 136 + k2]     = x0;
        *(uint4*)&hdS[n * 136 + k2 + 8] = x1;
    }
    {
        float4 v = ((const float4*)obsrow)[128 + t];
        int m = t >> 2, f0 = (t & 3) * 4;
        uint2 pkd = { pk2(v.x, v.y), pk2(v.z, v.w) };
        *(uint2*)&dockRm[m * 16 + f0] = pkd;
    }
    #pragma unroll
    for (int i = 0; i < 2; ++i) {
        int q4 = 384 + t + 256 * i;
        if (q4 < 896) {
            float4 v = ((const float4*)obsrow)[q4];
            int e = q4 * 4 - 1536;
            int n = e >> 6, m0 = e & 63;
            uint2 pkd = { pk2(v.x, v.y), pk2(v.z, v.w) };
            *(uint2*)&adjBf[n * 72 + m0] = pkd;
        }
    }
    ((uint4*)wdmTS)[t] = ((const uint4*)(wss + WS_WDMT_S))[t];
    #pragma unroll
    for (int i = 0; i < 8; ++i)
        ((uint4*)MtS)[t + 256 * i] = ((const uint4*)(wss + WS_MT_S))[t + 256 * i];
    if (t < 128) uL[t] = wsf[WS_U_F + t];
    else wL[t - 128] = wsf[WS_W_F + (t - 128)];
    __syncthreads();

    {
        int mt = w;
        short8 a;
        if (q < 2) a = *(const short8*)&dockRm[(mt * 16 + c) * 16 + q * 8];
        else a = short8{0, 0, 0, 0, 0, 0, 0, 0};
        float swp[4] = {0.f, 0.f, 0.f, 0.f};
        #pragma unroll
        for (int nt = 0; nt < 8; ++nt) {
            short8 bb;
            if (q < 2) bb = *(const short8*)&wdmTS[(nt * 16 + c) * 16 + q * 8];
            else bb = short8{0, 0, 0, 0, 0, 0, 0, 0};
            float4v acc = {0, 0, 0, 0};
            acc = __builtin_amdgcn_mfma_f32_16x16x32_bf16(a, bb, acc, 0, 0, 0);
            float wv = wL[nt * 16 + c];
            #pragma unroll
            for (int i = 0; i < 4; ++i) {
                float ev = elu_f(acc[i]);
                hkS[(mt * 16 + q * 4 + i) * 136 + nt * 16 + c] = f2bf(ev);
                swp[i] += ev * wv;
            }
        }
        #pragma unroll
        for (int i = 0; i < 4; ++i) {
            float sv = swp[i];
            sv += __shfl_xor(sv, 1, 16);
            sv += __shfl_xor(sv, 2, 16);
            sv += __shfl_xor(sv, 4, 16);
            sv += __shfl_xor(sv, 8, 16);
            if (c == 0) swL[mt * 16 + q * 4 + i] = sv;
        }
    }
    {
        int n = t >> 3, p = t & 7;
        float a = 0.f;
        #pragma unroll
        for (int kk = 0; kk < 16; kk += 2) {
            unsigned uu = *(const unsigned*)&hdS[n * 136 + p * 16 + kk];
            a += b2f((short)(uu & 0xffff)) * uL[p * 16 + kk]
               + b2f((short)(uu >> 16))   * uL[p * 16 + kk + 1];
        }
        a += __shfl_xor(a, 1, 8);
        a += __shfl_xor(a, 2, 8);
        a += __shfl_xor(a, 4, 8);
        if (p == 0) suL[n] = a;
    }
    __syncthreads();

    {
        int mt = w & 1, ntb = (w >> 1) * 4;
        float4v acc[4] = { {0,0,0,0}, {0,0,0,0}, {0,0,0,0}, {0,0,0,0} };
        #pragma unroll
        for (int kq = 0; kq < 4; ++kq) {
            short8 a = *(const short8*)&hdS[(mt * 16 + c) * 136 + kq * 32 + q * 8];
            #pragma unroll
            for (int p = 0; p < 4; ++p) {
                short8 bb = *(const short8*)&MtS[((ntb + p) * 16 + c) * 128 + kq * 32 + q * 8];
                acc[p] = __builtin_amdgcn_mfma_f32_16x16x32_bf16(a, bb, acc[p], 0, 0, 0);
            }
        }
        __syncthreads();
        #pragma unroll
        for (int p = 0; p < 4; ++p)
            #pragma unroll
            for (int i = 0; i < 4; ++i)
                t2S[(mt * 16 + q * 4 + i) * 136 + (ntb + p) * 16 + c] = f2bf(acc[p][i]);
    }
    __syncthreads();

    {
        const float c0v = wsf[WS_C0_F];
        int ntd = w;
        float* lg = out_logits + (size_t)b * 2048;
        #pragma unroll
        for (int mt = 0; mt < 2; ++mt) {
            float4v acc = {0, 0, 0, 0};
            #pragma unroll
            for (int kq = 0; kq < 4; ++kq) {
                short8 a  = *(const short8*)&t2S[(mt * 16 + c) * 136 + kq * 32 + q * 8];
                short8 bb = *(const short8*)&hkS[(ntd * 16 + c) * 136 + kq * 32 + q * 8];
                acc = __builtin_amdgcn_mfma_f32_16x16x32_bf16(a, bb, acc, 0, 0, 0);
            }
            int col = ntd * 16 + c;
            float swv = swL[col];
            #pragma unroll
            for (int i = 0; i < 4; ++i) {
                int row = mt * 16 + q * 4 + i;
                float val = acc[i] + suL[row] + swv + c0v;
                bool keep = b2f(adjBf[row * 72 + col]) > 0.f;
                lg[row * 64 + col] = keep ? val : NEGC;
            }
        }
    }
}

extern "C" void kernel_launch(void* const* d_in, const int* in_sizes, int n_in,
                              void* d_out, int out_size, void* d_ws, size_t ws_size,
                              hipStream_t stream) {
    (void)in_sizes; (void)n_in; (void)out_size;
    const float* obs     = (const float*)d_in[0];
    const float* W_drone = (const float*)d_in[1];
    const float* W_dock  = (const float*)d_in[2];
    const float* a_src   = (const float*)d_in[3];
    const float* a_dst   = (const float*)d_in[4];
    const float* Wc1     = (const float*)d_in[5];
    const float* bc1     = (const float*)d_in[6];
    const float* Wc2     = (const float*)d_in[7];
    const float* bc2     = (const float*)d_in[8];
    const float* Wad     = (const float*)d_in[9];
    const float* bad     = (const float*)d_in[10];
    const float* Wak     = (const float*)d_in[11];
    const float* bak     = (const float*)d_in[12];
    float* out = (float*)d_out;
    float* wsf = (float*)d_ws;
    short* wss = (short*)d_ws;

    const bool ws_wc1 = (ws_size >= WS_NEED_BYTES);
    const bool ws_hd  = (ws_size >= WS_NEED2_BYTES);

    setup_all<<<dim3(82), dim3(256), 0, stream>>>(
        W_drone, W_dock, a_src, a_dst, Wad, Wak, bad, bak, Wc1,
        wsf, wss, ws_wc1 ? 1 : 0);

    if (ws_hd) {
        short* hdw = wss + WS_HD_S;
        k13_fused<<<dim3(4096), dim3(256), 0, stream>>>(
            obs, wsf, wss, hdw, out + 4096);
        k2_critic4<<<dim3(256), dim3(256), 0, stream>>>(
            hdw, wss + WS_WC1H_S, wss + WS_WC1L_S, bc1, Wc2, bc2, out);
    } else {
        short* hdg = (short*)(out + 4096);   // HD stashed in logits region
        k1_attn_hd<<<dim3(4096), dim3(256), 0, stream>>>(obs, wsf, wss, hdg);
        if (ws_wc1)
            k2_critic4<<<dim3(256), dim3(256), 0, stream>>>(
                hdg, wss + WS_WC1H_S, wss + WS_WC1L_S, bc1, Wc2, bc2, out);
        else
            k2_critic<<<dim3(64), dim3(256), 0, stream>>>(hdg, Wc1, bc1, Wc2, bc2, out);
        k3_logits<<<dim3(4096), dim3(256), 0, stream>>>(obs, wsf, wss, out + 4096);
    }
}